// Round 3
// baseline (521.385 us; speedup 1.0000x reference)
//
#include <hip/hip_runtime.h>

#define PIX 262144   // 512*512
#define CCH 64
#define KK  16
// acc region layout (floats): counts[16*32] | sumsq[16*32] | psum[1024] | G[1024]
#define ACCN (512 + 512 + 1024 + 1024)

// ---------------- K1a: pack masks to 16-bit fields + counts via ballot --------------
__global__ __launch_bounds__(256) void k1a_pack(
        const int* __restrict__ masks, unsigned short* __restrict__ packed,
        float* __restrict__ counts) {
    int t = blockIdx.x * 256 + threadIdx.x;   // 512 blocks * 256 thr * 2 px = PIX
    int p = t * 2;
    unsigned m0 = 0, m1 = 0;
    #pragma unroll
    for (int k = 0; k < KK; ++k) {
        int2 mv = *(const int2*)(masks + (size_t)k * PIX + p);
        m0 |= (unsigned)(mv.x == 1) << k;
        m1 |= (unsigned)(mv.y == 1) << k;
    }
    packed[p]     = (unsigned short)m0;
    packed[p + 1] = (unsigned short)m1;

    __shared__ float wc[4][16];
    int wid = threadIdx.x >> 6, lane = threadIdx.x & 63;
    #pragma unroll
    for (int k = 0; k < KK; ++k) {
        unsigned long long b0 = __ballot((m0 >> k) & 1u);
        unsigned long long b1 = __ballot((m1 >> k) & 1u);
        if (lane == 0) wc[wid][k] = (float)(__popcll(b0) + __popcll(b1));
    }
    __syncthreads();
    if (threadIdx.x < 16) {
        int k = threadIdx.x;
        float s = wc[0][k] + wc[1][k] + wc[2][k] + wc[3][k];
        atomicAdd(counts + k * 32, s);
    }
}

// ---------------- K1b: y[p] = rsqrt(||X2col||^2), 4 px/thread, float4 ---------------
__global__ __launch_bounds__(256) void k1b_ynorm(
        const float* __restrict__ x2, float* __restrict__ yv) {
    int p = (blockIdx.x * 256 + threadIdx.x) * 4;   // 256 blocks
    float4 s = make_float4(0.f, 0.f, 0.f, 0.f);
    #pragma unroll 8
    for (int c = 0; c < CCH; ++c) {
        float4 v = *(const float4*)(x2 + (size_t)c * PIX + p);
        s.x = fmaf(v.x, v.x, s.x);
        s.y = fmaf(v.y, v.y, s.y);
        s.z = fmaf(v.z, v.z, s.z);
        s.w = fmaf(v.w, v.w, s.w);
    }
    float4 y;
    y.x = (s.x > 0.f) ? rsqrtf(s.x) : 0.f;
    y.y = (s.y > 0.f) ? rsqrtf(s.y) : 0.f;
    y.z = (s.z > 0.f) ? rsqrtf(s.z) : 0.f;
    y.w = (s.w > 0.f) ? rsqrtf(s.w) : 0.f;
    *(float4*)(yv + p) = y;
}

__device__ __forceinline__ float wred64(float v) {
    #pragma unroll
    for (int o = 32; o > 0; o >>= 1) v += __shfl_xor(v, o, 64);
    return v;
}

// ---------------- K2a: psum[k][c] = sum_p M X1, sumsq[k] ---------------------------
// 1024 blocks: g = channel group (4 ch), sl = 4096-px slice
__global__ __launch_bounds__(256)
__attribute__((amdgpu_waves_per_eu(2, 2)))
void k2a_x1(const float* __restrict__ x1, const unsigned short* __restrict__ packed,
            float* __restrict__ psum, float* __restrict__ sumsq) {
    int b = blockIdx.x;
    int g  = b & 15;
    int sl = b >> 4;
    int base = sl * 4096;
    int tid = threadIdx.x;

    float acc[4][16];
    float accS[16];
    #pragma unroll
    for (int c = 0; c < 4; ++c)
        #pragma unroll
        for (int k = 0; k < 16; ++k) acc[c][k] = 0.f;
    #pragma unroll
    for (int k = 0; k < 16; ++k) accS[k] = 0.f;

    const float* Xg = x1 + (size_t)(g * 4) * PIX;

    for (int pk = 0; pk < 4; ++pk) {
        int px = base + ((pk << 8) + tid) * 4;
        float4 xv[4];
        #pragma unroll
        for (int c = 0; c < 4; ++c) xv[c] = *(const float4*)(Xg + (size_t)c * PIX + px);
        ushort4 mv = *(const ushort4*)(packed + px);

        #pragma unroll
        for (int q = 0; q < 4; ++q) {
            unsigned m = (q == 0) ? mv.x : (q == 1) ? mv.y : (q == 2) ? mv.z : mv.w;
            float x0 = (q == 0) ? xv[0].x : (q == 1) ? xv[0].y : (q == 2) ? xv[0].z : xv[0].w;
            float x1e= (q == 0) ? xv[1].x : (q == 1) ? xv[1].y : (q == 2) ? xv[1].z : xv[1].w;
            float x2e= (q == 0) ? xv[2].x : (q == 1) ? xv[2].y : (q == 2) ? xv[2].z : xv[2].w;
            float x3 = (q == 0) ? xv[3].x : (q == 1) ? xv[3].y : (q == 2) ? xv[3].z : xv[3].w;
            float ss = x0 * x0;
            ss = fmaf(x1e, x1e, ss);
            ss = fmaf(x2e, x2e, ss);
            ss = fmaf(x3,  x3,  ss);
            #pragma unroll
            for (int k = 0; k < 16; ++k) {
                float f = (float)((m >> k) & 1u);
                acc[0][k] = fmaf(f, x0,  acc[0][k]);
                acc[1][k] = fmaf(f, x1e, acc[1][k]);
                acc[2][k] = fmaf(f, x2e, acc[2][k]);
                acc[3][k] = fmaf(f, x3,  acc[3][k]);
                accS[k]   = fmaf(f, ss,  accS[k]);
            }
        }
    }

    __shared__ float red[16][4][4];
    __shared__ float redS[16][4];
    int wid = tid >> 6, lane = tid & 63;
    #pragma unroll
    for (int k = 0; k < 16; ++k) {
        #pragma unroll
        for (int c = 0; c < 4; ++c) {
            float v = wred64(acc[c][k]);
            if (lane == 0) red[k][c][wid] = v;
        }
        float v = wred64(accS[k]);
        if (lane == 0) redS[k][wid] = v;
    }
    __syncthreads();
    if (tid < 64) {
        int k = tid >> 2, c = tid & 3;
        float s = red[k][c][0] + red[k][c][1] + red[k][c][2] + red[k][c][3];
        atomicAdd(psum + k * 64 + g * 4 + c, s);
    }
    if (tid < 16) {
        float s = redS[tid][0] + redS[tid][1] + redS[tid][2] + redS[tid][3];
        atomicAdd(sumsq + tid * 32, s);
    }
}

// ---------------- K2b: G[k][c] = sum_p M y X2 --------------------------------------
__global__ __launch_bounds__(256)
__attribute__((amdgpu_waves_per_eu(2, 2)))
void k2b_x2(const float* __restrict__ x2, const unsigned short* __restrict__ packed,
            const float* __restrict__ yv, float* __restrict__ G) {
    int b = blockIdx.x;
    int g  = b & 15;
    int sl = b >> 4;
    int base = sl * 4096;
    int tid = threadIdx.x;

    float acc[4][16];
    #pragma unroll
    for (int c = 0; c < 4; ++c)
        #pragma unroll
        for (int k = 0; k < 16; ++k) acc[c][k] = 0.f;

    const float* Xg = x2 + (size_t)(g * 4) * PIX;

    for (int pk = 0; pk < 4; ++pk) {
        int px = base + ((pk << 8) + tid) * 4;
        float4 xv[4];
        #pragma unroll
        for (int c = 0; c < 4; ++c) xv[c] = *(const float4*)(Xg + (size_t)c * PIX + px);
        ushort4 mv = *(const ushort4*)(packed + px);
        float4 yv4 = *(const float4*)(yv + px);

        #pragma unroll
        for (int q = 0; q < 4; ++q) {
            unsigned m = (q == 0) ? mv.x : (q == 1) ? mv.y : (q == 2) ? mv.z : mv.w;
            float w  = (q == 0) ? yv4.x : (q == 1) ? yv4.y : (q == 2) ? yv4.z : yv4.w;
            float x0 = ((q == 0) ? xv[0].x : (q == 1) ? xv[0].y : (q == 2) ? xv[0].z : xv[0].w) * w;
            float x1e= ((q == 0) ? xv[1].x : (q == 1) ? xv[1].y : (q == 2) ? xv[1].z : xv[1].w) * w;
            float x2e= ((q == 0) ? xv[2].x : (q == 1) ? xv[2].y : (q == 2) ? xv[2].z : xv[2].w) * w;
            float x3 = ((q == 0) ? xv[3].x : (q == 1) ? xv[3].y : (q == 2) ? xv[3].z : xv[3].w) * w;
            #pragma unroll
            for (int k = 0; k < 16; ++k) {
                float f = (float)((m >> k) & 1u);
                acc[0][k] = fmaf(f, x0,  acc[0][k]);
                acc[1][k] = fmaf(f, x1e, acc[1][k]);
                acc[2][k] = fmaf(f, x2e, acc[2][k]);
                acc[3][k] = fmaf(f, x3,  acc[3][k]);
            }
        }
    }

    __shared__ float red[16][4][4];
    int wid = tid >> 6, lane = tid & 63;
    #pragma unroll
    for (int k = 0; k < 16; ++k) {
        #pragma unroll
        for (int c = 0; c < 4; ++c) {
            float v = wred64(acc[c][k]);
            if (lane == 0) red[k][c][wid] = v;
        }
    }
    __syncthreads();
    if (tid < 64) {
        int k = tid >> 2, c = tid & 3;
        float s = red[k][c][0] + red[k][c][1] + red[k][c][2] + red[k][c][3];
        atomicAdd(G + k * 64 + g * 4 + c, s);
    }
}

// ---------------- K3: finalize ------------------------------------------------------
__global__ __launch_bounds__(256) void k3_finalize(
        const int* __restrict__ labels, const float* __restrict__ counts,
        const float* __restrict__ psum, const float* __restrict__ sumsq,
        const float* __restrict__ G, float* __restrict__ out) {
    __shared__ float meansS[16][64];
    __shared__ float Gs[16][64];
    __shared__ float cntS[16], rawcS[16], nmS[16], stdS[16];
    __shared__ float simS[16][16];
    int t = threadIdx.x;

    if (t < 16) {
        float c0 = counts[t * 32];
        rawcS[t] = c0;
        cntS[t] = fmaxf(c0, 1.f);
    }
    __syncthreads();
    for (int i = t; i < 1024; i += 256) {
        int k = i >> 6, c = i & 63;
        meansS[k][c] = psum[i] / cntS[k];
        Gs[k][c] = G[i];
    }
    __syncthreads();
    if (t < 16) {
        float s = 0.f, sa = 0.f;
        for (int c = 0; c < 64; ++c) {
            s = fmaf(meansS[t][c], meansS[t][c], s);
            sa += psum[t * 64 + c];
        }
        nmS[t] = sqrtf(s);
        float ne = rawcS[t] * 64.f;
        float ma = sa / fmaxf(ne, 1.f);
        float var = (sumsq[t * 32] - ne * ma * ma) / fmaxf(ne - 1.f, 1.f);
        stdS[t] = sqrtf(fmaxf(var, 0.f));
    }
    __syncthreads();
    {
        int i = t >> 4, j = t & 15;
        float d = 0.f;
        for (int c = 0; c < 64; ++c) d = fmaf(meansS[i][c], Gs[j][c], d);
        simS[i][j] = d / (fmaxf(nmS[i], 1e-30f) * cntS[j]);
    }
    __syncthreads();
    if (t == 0) {
        int lab[16];
        for (int k = 0; k < 16; ++k) lab[k] = labels[k];
        float cc[11], inst[11], csim[11], cstd[11];
        for (int l = 0; l < 11; ++l) { cc[l]=0.f; inst[l]=0.f; csim[l]=0.f; cstd[l]=0.f; }
        for (int k = 0; k < 16; ++k) cc[lab[k]] += 1.f;
        for (int k = 0; k < 16; ++k) inst[lab[k]] += simS[k][k];
        for (int i = 0; i < 16; ++i) {
            float row = 0.f;
            for (int j = 0; j < 16; ++j)
                if (j != i && lab[j] == lab[i]) row += simS[i][j];
            csim[lab[i]] += row;
        }
        for (int k = 0; k < 16; ++k) cstd[lab[k]] += stdS[k];
        float nb[3];
        for (int bq = 0; bq < 3; ++bq) {
            float c = 0.f, s = 0.f;
            for (int i = 0; i < 16; ++i) {
                for (int j = 0; j < 16; ++j) {
                    if (lab[i] == lab[j]) continue;
                    bool gi, gj;
                    if (bq == 0)      { gi = lab[i] >= 1 && lab[i] <= 8;  gj = lab[j] >= 1 && lab[j] <= 8; }
                    else if (bq == 1) { gi = lab[i] >= 3 && lab[i] <= 10; gj = lab[j] >= 3 && lab[j] <= 10; }
                    else { gi = (lab[i] >= 1 && lab[i] <= 2) || (lab[i] >= 9 && lab[i] <= 10);
                           gj = (lab[j] >= 1 && lab[j] <= 2) || (lab[j] >= 9 && lab[j] <= 10); }
                    if (gi && gj) { c += 1.f; s += simS[i][j]; }
                }
            }
            nb[bq] = (c > 1.f) ? (s / c) : s;
        }
        for (int l = 0; l < 11; ++l) {
            if (cc[l] > 1.f) {
                inst[l] /= fmaxf(cc[l], 1.f);
                csim[l] /= fmaxf(cc[l] * (cc[l] - 1.f), 1.f);
                cstd[l] /= cc[l];
            }
            out[l]      = inst[l];
            out[11 + l] = csim[l];
            out[25 + l] = cstd[l];
        }
        out[22] = nb[0];
        out[23] = nb[1];
        out[24] = nb[2];
    }
}

extern "C" void kernel_launch(void* const* d_in, const int* in_sizes, int n_in,
                              void* d_out, int out_size, void* d_ws, size_t ws_size,
                              hipStream_t stream) {
    const float* x1     = (const float*)d_in[0];
    const float* x2     = (const float*)d_in[1];
    const int*   masks  = (const int*)d_in[2];
    const int*   labels = (const int*)d_in[3];
    float* out = (float*)d_out;

    char* ws = (char*)d_ws;
    unsigned short* packed = (unsigned short*)ws;                  // PIX*2 bytes
    float* yv  = (float*)(ws + (size_t)PIX * 2);                   // PIX*4 bytes
    float* acc = (float*)(ws + (size_t)PIX * 2 + (size_t)PIX * 4); // ACCN floats
    float* counts = acc;            // stride-32 padded, 16 entries
    float* sumsq  = acc + 512;      // stride-32 padded, 16 entries
    float* psum   = acc + 1024;     // [16][64]
    float* Gacc   = acc + 2048;     // [16][64]

    hipMemsetAsync(acc, 0, (size_t)ACCN * sizeof(float), stream);
    k1a_pack<<<512, 256, 0, stream>>>(masks, packed, counts);
    k1b_ynorm<<<256, 256, 0, stream>>>(x2, yv);
    k2a_x1<<<1024, 256, 0, stream>>>(x1, packed, psum, sumsq);
    k2b_x2<<<1024, 256, 0, stream>>>(x2, packed, yv, Gacc);
    k3_finalize<<<1, 256, 0, stream>>>(labels, counts, psum, sumsq, Gacc, out);
}

// Round 4
// 239.345 us; speedup vs baseline: 2.1784x; 2.1784x over previous
//
#include <hip/hip_runtime.h>

#define PIX 262144   // 512*512
#define CCH 64
#define KK  16
#define NSL 32       // slices per k2 kernel

// ws float layout (after packed/yv):
//   counts_s  [16][32]      (atomic-spread, memset to 0)
//   sumsq_part[512][16]     (owned writes)
//   psum_part [32][16][64]  (owned writes)
//   G_part    [32][16][64]  (owned writes)

// ---------------- K1a: pack masks + spread-atomic counts ---------------------------
__global__ __launch_bounds__(256) void k1a_pack(
        const int* __restrict__ masks, unsigned short* __restrict__ packed,
        float* __restrict__ counts_s) {
    int t = blockIdx.x * 256 + threadIdx.x;   // 512 blocks * 256 thr * 2 px = PIX
    int p = t * 2;
    unsigned m0 = 0, m1 = 0;
    #pragma unroll
    for (int k = 0; k < KK; ++k) {
        int2 mv = *(const int2*)(masks + (size_t)k * PIX + p);
        m0 |= (unsigned)(mv.x == 1) << k;
        m1 |= (unsigned)(mv.y == 1) << k;
    }
    packed[p]     = (unsigned short)m0;
    packed[p + 1] = (unsigned short)m1;

    __shared__ float wc[4][16];
    int wid = threadIdx.x >> 6, lane = threadIdx.x & 63;
    #pragma unroll
    for (int k = 0; k < KK; ++k) {
        unsigned long long b0 = __ballot((m0 >> k) & 1u);
        unsigned long long b1 = __ballot((m1 >> k) & 1u);
        if (lane == 0) wc[wid][k] = (float)(__popcll(b0) + __popcll(b1));
    }
    __syncthreads();
    if (threadIdx.x < 16) {
        int k = threadIdx.x;
        float s = wc[0][k] + wc[1][k] + wc[2][k] + wc[3][k];
        atomicAdd(counts_s + k * 32 + (blockIdx.x & 31), s);
    }
}

// ---------------- K1b: y[p] = rsqrt(||X2col||^2), 2 px/thread ----------------------
__global__ __launch_bounds__(256) void k1b_ynorm(
        const float* __restrict__ x2, float* __restrict__ yv) {
    int p = (blockIdx.x * 256 + threadIdx.x) * 2;   // 512 blocks
    float s0 = 0.f, s1 = 0.f;
    #pragma unroll 16
    for (int c = 0; c < CCH; ++c) {
        float2 v = *(const float2*)(x2 + (size_t)c * PIX + p);
        s0 = fmaf(v.x, v.x, s0);
        s1 = fmaf(v.y, v.y, s1);
    }
    float2 y;
    y.x = (s0 > 0.f) ? rsqrtf(s0) : 0.f;
    y.y = (s1 > 0.f) ? rsqrtf(s1) : 0.f;
    *(float2*)(yv + p) = y;
}

__device__ __forceinline__ float wred64(float v) {
    #pragma unroll
    for (int o = 32; o > 0; o >>= 1) v += __shfl_xor(v, o, 64);
    return v;
}

// ---------------- K2a: psum_part + sumsq_part (X1), owned writes, no atomics -------
__global__ __launch_bounds__(256)
__attribute__((amdgpu_waves_per_eu(2, 2)))
void k2a_x1(const float* __restrict__ x1, const unsigned short* __restrict__ packed,
            float* __restrict__ psum_part, float* __restrict__ sumsq_part) {
    int b = blockIdx.x;       // 512 = 16 g * 32 sl
    int g  = b & 15;
    int sl = b >> 4;
    int base = sl * (PIX / NSL);   // 8192-px slice
    int tid = threadIdx.x;

    float acc[4][16];
    float accS[16];
    #pragma unroll
    for (int c = 0; c < 4; ++c)
        #pragma unroll
        for (int k = 0; k < 16; ++k) acc[c][k] = 0.f;
    #pragma unroll
    for (int k = 0; k < 16; ++k) accS[k] = 0.f;

    const float* Xg = x1 + (size_t)(g * 4) * PIX;

    for (int pk = 0; pk < 8; ++pk) {
        int px = base + ((pk << 8) + tid) * 4;
        float4 xv[4];
        #pragma unroll
        for (int c = 0; c < 4; ++c) xv[c] = *(const float4*)(Xg + (size_t)c * PIX + px);
        ushort4 mv = *(const ushort4*)(packed + px);

        #pragma unroll
        for (int q = 0; q < 4; ++q) {
            unsigned m = (q == 0) ? mv.x : (q == 1) ? mv.y : (q == 2) ? mv.z : mv.w;
            float x0 = (q == 0) ? xv[0].x : (q == 1) ? xv[0].y : (q == 2) ? xv[0].z : xv[0].w;
            float x1e= (q == 0) ? xv[1].x : (q == 1) ? xv[1].y : (q == 2) ? xv[1].z : xv[1].w;
            float x2e= (q == 0) ? xv[2].x : (q == 1) ? xv[2].y : (q == 2) ? xv[2].z : xv[2].w;
            float x3 = (q == 0) ? xv[3].x : (q == 1) ? xv[3].y : (q == 2) ? xv[3].z : xv[3].w;
            float ss = x0 * x0;
            ss = fmaf(x1e, x1e, ss);
            ss = fmaf(x2e, x2e, ss);
            ss = fmaf(x3,  x3,  ss);
            #pragma unroll
            for (int k = 0; k < 16; ++k) {
                float f = (float)((m >> k) & 1u);
                acc[0][k] = fmaf(f, x0,  acc[0][k]);
                acc[1][k] = fmaf(f, x1e, acc[1][k]);
                acc[2][k] = fmaf(f, x2e, acc[2][k]);
                acc[3][k] = fmaf(f, x3,  acc[3][k]);
                accS[k]   = fmaf(f, ss,  accS[k]);
            }
        }
    }

    __shared__ float red[16][4][4];
    __shared__ float redS[16][4];
    int wid = tid >> 6, lane = tid & 63;
    #pragma unroll
    for (int k = 0; k < 16; ++k) {
        #pragma unroll
        for (int c = 0; c < 4; ++c) {
            float v = wred64(acc[c][k]);
            if (lane == 0) red[k][c][wid] = v;
        }
        float v = wred64(accS[k]);
        if (lane == 0) redS[k][wid] = v;
    }
    __syncthreads();
    if (tid < 64) {
        int k = tid >> 2, c = tid & 3;
        float s = red[k][c][0] + red[k][c][1] + red[k][c][2] + red[k][c][3];
        psum_part[sl * 1024 + k * 64 + g * 4 + c] = s;
    }
    if (tid < 16) {
        float s = redS[tid][0] + redS[tid][1] + redS[tid][2] + redS[tid][3];
        sumsq_part[(sl * 16 + g) * 16 + tid] = s;
    }
}

// ---------------- K2b: G_part (y * X2), owned writes, no atomics -------------------
__global__ __launch_bounds__(256)
__attribute__((amdgpu_waves_per_eu(2, 2)))
void k2b_x2(const float* __restrict__ x2, const unsigned short* __restrict__ packed,
            const float* __restrict__ yv, float* __restrict__ G_part) {
    int b = blockIdx.x;       // 512
    int g  = b & 15;
    int sl = b >> 4;
    int base = sl * (PIX / NSL);
    int tid = threadIdx.x;

    float acc[4][16];
    #pragma unroll
    for (int c = 0; c < 4; ++c)
        #pragma unroll
        for (int k = 0; k < 16; ++k) acc[c][k] = 0.f;

    const float* Xg = x2 + (size_t)(g * 4) * PIX;

    for (int pk = 0; pk < 8; ++pk) {
        int px = base + ((pk << 8) + tid) * 4;
        float4 xv[4];
        #pragma unroll
        for (int c = 0; c < 4; ++c) xv[c] = *(const float4*)(Xg + (size_t)c * PIX + px);
        ushort4 mv = *(const ushort4*)(packed + px);
        float4 yv4 = *(const float4*)(yv + px);

        #pragma unroll
        for (int q = 0; q < 4; ++q) {
            unsigned m = (q == 0) ? mv.x : (q == 1) ? mv.y : (q == 2) ? mv.z : mv.w;
            float w  = (q == 0) ? yv4.x : (q == 1) ? yv4.y : (q == 2) ? yv4.z : yv4.w;
            float x0 = ((q == 0) ? xv[0].x : (q == 1) ? xv[0].y : (q == 2) ? xv[0].z : xv[0].w) * w;
            float x1e= ((q == 0) ? xv[1].x : (q == 1) ? xv[1].y : (q == 2) ? xv[1].z : xv[1].w) * w;
            float x2e= ((q == 0) ? xv[2].x : (q == 1) ? xv[2].y : (q == 2) ? xv[2].z : xv[2].w) * w;
            float x3 = ((q == 0) ? xv[3].x : (q == 1) ? xv[3].y : (q == 2) ? xv[3].z : xv[3].w) * w;
            #pragma unroll
            for (int k = 0; k < 16; ++k) {
                float f = (float)((m >> k) & 1u);
                acc[0][k] = fmaf(f, x0,  acc[0][k]);
                acc[1][k] = fmaf(f, x1e, acc[1][k]);
                acc[2][k] = fmaf(f, x2e, acc[2][k]);
                acc[3][k] = fmaf(f, x3,  acc[3][k]);
            }
        }
    }

    __shared__ float red[16][4][4];
    int wid = tid >> 6, lane = tid & 63;
    #pragma unroll
    for (int k = 0; k < 16; ++k) {
        #pragma unroll
        for (int c = 0; c < 4; ++c) {
            float v = wred64(acc[c][k]);
            if (lane == 0) red[k][c][wid] = v;
        }
    }
    __syncthreads();
    if (tid < 64) {
        int k = tid >> 2, c = tid & 3;
        float s = red[k][c][0] + red[k][c][1] + red[k][c][2] + red[k][c][3];
        G_part[sl * 1024 + k * 64 + g * 4 + c] = s;
    }
}

// ---------------- K3: reduce partials + finalize (fully parallel, LDS only) --------
__global__ __launch_bounds__(256) void k3_finalize(
        const int* __restrict__ labels, const float* __restrict__ counts_s,
        const float* __restrict__ psum_part, const float* __restrict__ sumsq_part,
        const float* __restrict__ G_part, float* __restrict__ out) {
    __shared__ float meansS[16][65];
    __shared__ float Gs[16][65];
    __shared__ float cntS[16], rawcS[16], nmS[16], stdS[16], rowS[16];
    __shared__ float ssq2[16][17];
    __shared__ float ssqS[16];
    __shared__ int   labS[16];
    __shared__ float simS[16][17];
    __shared__ float bred[4][6];
    int t = threadIdx.x;

    if (t < 16) {
        float s = 0.f;
        #pragma unroll 8
        for (int j = 0; j < 32; ++j) s += counts_s[t * 32 + j];
        rawcS[t] = s;
        cntS[t]  = fmaxf(s, 1.f);
        labS[t]  = labels[t];
    }
    // sumsq partial reduce: thread (k = t&15, rg = t>>4) sums 32 of 512 rows
    {
        int k = t & 15, rg = t >> 4;
        float s = 0.f;
        #pragma unroll 8
        for (int r = rg * 32; r < rg * 32 + 32; ++r) s += sumsq_part[r * 16 + k];
        ssq2[k][rg] = s;
    }
    __syncthreads();
    if (t < 16) {
        float s = 0.f;
        #pragma unroll
        for (int rg = 0; rg < 16; ++rg) s += ssq2[t][rg];
        ssqS[t] = s;
    }
    // psum/G slice reduce -> means, Gs
    for (int i = t; i < 1024; i += 256) {
        int k = i >> 6, c = i & 63;
        float sp = 0.f, sg = 0.f;
        #pragma unroll 8
        for (int sl = 0; sl < NSL; ++sl) {
            sp += psum_part[sl * 1024 + i];
            sg += G_part[sl * 1024 + i];
        }
        meansS[k][c] = sp / cntS[k];
        Gs[k][c] = sg;
    }
    __syncthreads();
    if (t < 16) {
        float s2 = 0.f, sm = 0.f;
        for (int c = 0; c < 64; ++c) {
            float m = meansS[t][c];
            s2 = fmaf(m, m, s2);
            sm += m;
        }
        nmS[t] = sqrtf(s2);
        float ne = rawcS[t] * 64.f;
        float ma = (sm * cntS[t]) / fmaxf(ne, 1.f);   // == sum_all / max(n_elem,1)
        float var = (ssqS[t] - ne * ma * ma) / fmaxf(ne - 1.f, 1.f);
        stdS[t] = sqrtf(fmaxf(var, 0.f));
    }
    __syncthreads();
    {
        int i = t >> 4, j = t & 15;
        float d = 0.f;
        #pragma unroll 16
        for (int c = 0; c < 64; ++c) d = fmaf(meansS[i][c], Gs[j][c], d);
        simS[i][j] = d / (fmaxf(nmS[i], 1e-30f) * cntS[j]);
    }
    __syncthreads();
    if (t < 16) {
        float s = 0.f;
        int li = labS[t];
        for (int j = 0; j < 16; ++j)
            if (j != t && labS[j] == li) s += simS[t][j];
        rowS[t] = s;
    }
    // neg buckets: one pair per thread, block reduce
    float s0 = 0.f, s1 = 0.f, s2 = 0.f, c0 = 0.f, c1 = 0.f, c2 = 0.f;
    {
        int i = t >> 4, j = t & 15;
        int li = labS[i], lj = labS[j];
        if (li != lj) {
            float sv = simS[i][j];
            bool gi0 = li >= 1 && li <= 8,  gj0 = lj >= 1 && lj <= 8;
            bool gi1 = li >= 3 && li <= 10, gj1 = lj >= 3 && lj <= 10;
            bool gi2 = (li >= 1 && li <= 2) || (li >= 9 && li <= 10);
            bool gj2 = (lj >= 1 && lj <= 2) || (lj >= 9 && lj <= 10);
            if (gi0 && gj0) { s0 = sv; c0 = 1.f; }
            if (gi1 && gj1) { s1 = sv; c1 = 1.f; }
            if (gi2 && gj2) { s2 = sv; c2 = 1.f; }
        }
    }
    s0 = wred64(s0); s1 = wred64(s1); s2 = wred64(s2);
    c0 = wred64(c0); c1 = wred64(c1); c2 = wred64(c2);
    {
        int wid = t >> 6, lane = t & 63;
        if (lane == 0) {
            bred[wid][0] = s0; bred[wid][1] = s1; bred[wid][2] = s2;
            bred[wid][3] = c0; bred[wid][4] = c1; bred[wid][5] = c2;
        }
    }
    __syncthreads();
    if (t < 11) {
        float cc = 0.f, inst = 0.f, csim = 0.f, cstd = 0.f;
        for (int k = 0; k < 16; ++k) {
            if (labS[k] == t) {
                cc += 1.f;
                inst += simS[k][k];
                csim += rowS[k];
                cstd += stdS[k];
            }
        }
        if (cc > 1.f) {
            inst /= fmaxf(cc, 1.f);
            csim /= fmaxf(cc * (cc - 1.f), 1.f);
            cstd /= cc;
        }
        out[t]      = inst;
        out[11 + t] = csim;
        out[25 + t] = cstd;
    }
    if (t == 0) {
        float S0 = bred[0][0] + bred[1][0] + bred[2][0] + bred[3][0];
        float S1 = bred[0][1] + bred[1][1] + bred[2][1] + bred[3][1];
        float S2 = bred[0][2] + bred[1][2] + bred[2][2] + bred[3][2];
        float C0 = bred[0][3] + bred[1][3] + bred[2][3] + bred[3][3];
        float C1 = bred[0][4] + bred[1][4] + bred[2][4] + bred[3][4];
        float C2 = bred[0][5] + bred[1][5] + bred[2][5] + bred[3][5];
        out[22] = (C0 > 1.f) ? (S0 / C0) : S0;
        out[23] = (C1 > 1.f) ? (S1 / C1) : S1;
        out[24] = (C2 > 1.f) ? (S2 / C2) : S2;
    }
}

extern "C" void kernel_launch(void* const* d_in, const int* in_sizes, int n_in,
                              void* d_out, int out_size, void* d_ws, size_t ws_size,
                              hipStream_t stream) {
    const float* x1     = (const float*)d_in[0];
    const float* x2     = (const float*)d_in[1];
    const int*   masks  = (const int*)d_in[2];
    const int*   labels = (const int*)d_in[3];
    float* out = (float*)d_out;

    char* ws = (char*)d_ws;
    unsigned short* packed = (unsigned short*)ws;                    // 512 KB
    float* yv         = (float*)(ws + (size_t)PIX * 2);              // 1 MB
    float* counts_s   = (float*)(ws + (size_t)PIX * 6);              // 512 f
    float* sumsq_part = counts_s + 512;                              // 8192 f
    float* psum_part  = sumsq_part + 8192;                           // 32768 f
    float* G_part     = psum_part + 32768;                           // 32768 f

    hipMemsetAsync(counts_s, 0, 512 * sizeof(float), stream);
    k1a_pack<<<512, 256, 0, stream>>>(masks, packed, counts_s);
    k1b_ynorm<<<512, 256, 0, stream>>>(x2, yv);
    k2a_x1<<<512, 256, 0, stream>>>(x1, packed, psum_part, sumsq_part);
    k2b_x2<<<512, 256, 0, stream>>>(x2, packed, yv, G_part);
    k3_finalize<<<1, 256, 0, stream>>>(labels, counts_s, psum_part, sumsq_part, G_part, out);
}